// Round 1
// baseline (838.555 us; speedup 1.0000x reference)
//
#include <hip/hip_runtime.h>

// Problem constants (from reference)
#define TT 8192      // tokens = N*P
#define DM 512       // d_model
#define DH 2048      // d_inner
#define NE 8         // experts
// TOP_K = 2, folded into gate weights as *0.5f

// ---------------------------------------------------------------------------
// Kernel 1: gating. One wave per token: 8 logits (dot over 512), softmax,
// top-2, bucket (expert -> token list) via atomics.
// ---------------------------------------------------------------------------
__global__ __launch_bounds__(256) void moe_gating(
    const float* __restrict__ x, const float* __restrict__ gw,
    const float* __restrict__ gb, int* __restrict__ counts,
    int* __restrict__ tok_list, float* __restrict__ w_list)
{
    __shared__ float xs[4][DM];
    const int wv = threadIdx.x >> 6, ln = threadIdx.x & 63;
    const int t = (blockIdx.x << 2) + wv;
    const float* xp = x + (size_t)t * DM;
    for (int i = ln; i < DM; i += 64) xs[wv][i] = xp[i];
    __syncthreads();

    const int e = ln & 7, g = ln >> 3;         // lane -> (expert, 1/8 of dot)
    const float* wp = gw + e * DM;
    float acc = 0.f;
#pragma unroll 8
    for (int j = 0; j < 64; ++j) {
        const int d = g + (j << 3);
        acc = fmaf(xs[wv][d], wp[d], acc);
    }
    // reduce over the 8 lane-groups (lane&7 == e preserved under xor 8/16/32)
    acc += __shfl_xor(acc, 8);
    acc += __shfl_xor(acc, 16);
    acc += __shfl_xor(acc, 32);
    const float logit = acc + gb[e];           // lane j (j<8) holds expert j's logit

    float lg[8];
#pragma unroll
    for (int j = 0; j < 8; ++j) lg[j] = __shfl(logit, j);

    if (ln == 0) {
        float m = lg[0];
#pragma unroll
        for (int j = 1; j < 8; ++j) m = fmaxf(m, lg[j]);
        float s = 0.f, ex[8];
#pragma unroll
        for (int j = 0; j < 8; ++j) { ex[j] = expf(lg[j] - m); s += ex[j]; }
        // top-2 on logits (softmax monotonic); ties -> lowest index, like lax.top_k
        int i0 = 0;
#pragma unroll
        for (int j = 1; j < 8; ++j) if (lg[j] > lg[i0]) i0 = j;
        int i1 = (i0 == 0) ? 1 : 0;
#pragma unroll
        for (int j = 0; j < 8; ++j) if (j != i0 && lg[j] > lg[i1]) i1 = j;
        const float inv = 0.5f / s;            // fold 1/TOP_K here
        const int p0 = atomicAdd(&counts[i0], 1);
        tok_list[i0 * TT + p0] = t; w_list[i0 * TT + p0] = ex[i0] * inv;
        const int p1 = atomicAdd(&counts[i1], 1);
        tok_list[i1 * TT + p1] = t; w_list[i1 * TT + p1] = ex[i1] * inv;
    }
}

// ---------------------------------------------------------------------------
// Kernel 2: grouped GEMM, one expert per blockIdx.z. Tile 128x128, BK=32,
// 256 threads, 8x8 per thread as 2x2 blocks of 4x4 (float4 LDS reads,
// <=2-way bank aliasing). Epilogue: out[tok][h] += w * (acc + bias[e][h]).
// ---------------------------------------------------------------------------
#define BM 128
#define BN 128
#define BK 32
#define LDA (BM + 4)   // 132 floats: row stride 528B (16B-aligned, shifts banks)
#define LDB (BN + 4)

__global__ __launch_bounds__(256) void moe_gemm(
    const float* __restrict__ x, const float* __restrict__ W,
    const float* __restrict__ Bb, const int* __restrict__ counts,
    const int* __restrict__ tok_list, const float* __restrict__ w_list,
    float* __restrict__ out)
{
    const int e = blockIdx.z;
    const int cnt = counts[e];
    const int row0 = blockIdx.y * BM;
    if (row0 >= cnt) return;                   // empty tile
    const int rem = cnt - row0;                // valid rows in this tile (cap BM)
    const int h0 = blockIdx.x * BN;

    __shared__ float as[BK][LDA];
    __shared__ float bs[BK][LDB];
    __shared__ int   tok_s[BM];
    __shared__ float wgt_s[BM];

    const int tid = threadIdx.x;
    if (tid < BM) {
        const int ok = (tid < rem);
        tok_s[tid] = ok ? tok_list[e * TT + row0 + tid] : 0;
        wgt_s[tid] = ok ? w_list[e * TT + row0 + tid] : 0.f;
    }
    __syncthreads();

    const int tx = tid & 15, ty = tid >> 4;

    // A staging: 128 rows x 32 k, 2 threads/row, 4x float4 each along k
    const int ar   = tid >> 1;
    const int a_k0 = (tid & 1) << 4;
    const float* xrow = x + (size_t)tok_s[ar] * DM;

    // B staging: 32 k-rows x 128 cols, 8 threads/row, 4x float4 each
    const int bkr = tid >> 3;
    const int bc0 = (tid & 7) << 4;
    const float* wbase = W + (size_t)e * DM * DH + h0;

    float c[2][2][4][4] = {};

    for (int k0 = 0; k0 < DM; k0 += BK) {
#pragma unroll
        for (int i = 0; i < 4; ++i) {
            const int kk = a_k0 + (i << 2);
            const float4 v = *(const float4*)&xrow[k0 + kk];
            as[kk + 0][ar] = v.x; as[kk + 1][ar] = v.y;
            as[kk + 2][ar] = v.z; as[kk + 3][ar] = v.w;
        }
        const float* wp0 = wbase + (size_t)(k0 + bkr) * DH + bc0;
#pragma unroll
        for (int i = 0; i < 4; ++i)
            *(float4*)&bs[bkr][bc0 + (i << 2)] = *(const float4*)(wp0 + (i << 2));
        __syncthreads();

#pragma unroll
        for (int k = 0; k < BK; ++k) {
            const float4 a0 = *(const float4*)&as[k][(ty << 2)];
            const float4 a1 = *(const float4*)&as[k][64 + (ty << 2)];
            const float4 b0 = *(const float4*)&bs[k][(tx << 2)];
            const float4 b1 = *(const float4*)&bs[k][64 + (tx << 2)];
            const float av[2][4] = {{a0.x, a0.y, a0.z, a0.w}, {a1.x, a1.y, a1.z, a1.w}};
            const float bv[2][4] = {{b0.x, b0.y, b0.z, b0.w}, {b1.x, b1.y, b1.z, b1.w}};
#pragma unroll
            for (int p = 0; p < 2; ++p)
#pragma unroll
            for (int i = 0; i < 4; ++i)
#pragma unroll
            for (int q = 0; q < 2; ++q)
#pragma unroll
            for (int j = 0; j < 4; ++j)
                c[p][q][i][j] = fmaf(av[p][i], bv[q][j], c[p][q][i][j]);
        }
        __syncthreads();
    }

    const float* be = Bb + (size_t)e * DH + h0;
#pragma unroll
    for (int p = 0; p < 2; ++p)
#pragma unroll
    for (int i = 0; i < 4; ++i) {
        const int r = (p << 6) + (ty << 2) + i;
        if (r < rem) {
            const float w = wgt_s[r];
            float* orow = out + (size_t)tok_s[r] * DH + h0;
#pragma unroll
            for (int q = 0; q < 2; ++q)
#pragma unroll
            for (int j = 0; j < 4; ++j) {
                const int col = (q << 6) + (tx << 2) + j;
                unsafeAtomicAdd(&orow[col], w * (c[p][q][i][j] + be[col]));
            }
        }
    }
}

// ---------------------------------------------------------------------------
extern "C" void kernel_launch(void* const* d_in, const int* in_sizes, int n_in,
                              void* d_out, int out_size, void* d_ws, size_t ws_size,
                              hipStream_t stream) {
    const float* seq = (const float*)d_in[0];   // [4,2048,512]
    const float* ew  = (const float*)d_in[1];   // [8,512,2048]
    const float* eb  = (const float*)d_in[2];   // [8,2048]
    const float* gw  = (const float*)d_in[3];   // [8,512]
    const float* gb  = (const float*)d_in[4];   // [8]
    float* out = (float*)d_out;                 // [8192,2048]

    char* ws = (char*)d_ws;
    int*   counts   = (int*)ws;                          // 8 ints
    int*   tok_list = (int*)(ws + 1024);                 // 8*8192 ints = 256KB
    float* w_list   = (float*)(ws + 1024 + NE * TT * 4); // 8*8192 floats = 256KB

    hipMemsetAsync(counts, 0, NE * sizeof(int), stream);
    hipMemsetAsync(out, 0, (size_t)TT * DH * sizeof(float), stream);

    moe_gating<<<TT / 4, 256, 0, stream>>>(seq, gw, gb, counts, tok_list, w_list);

    dim3 grid(DH / BN, TT / BM, NE);
    moe_gemm<<<grid, 256, 0, stream>>>(seq, ew, eb, counts, tok_list, w_list, out);
}

// Round 6
// 413.348 us; speedup vs baseline: 2.0287x; 2.0287x over previous
//
#include <hip/hip_runtime.h>
#include <hip/hip_bf16.h>

#define TT 8192      // tokens = N*P
#define DM 512       // d_model
#define DH 2048      // d_inner
#define NE 8         // experts
// TOP_K = 2 folded into gate weights as *0.5f

typedef short short8 __attribute__((ext_vector_type(8)));
typedef float f32x4  __attribute__((ext_vector_type(4)));

#define GL16(g, l) __builtin_amdgcn_global_load_lds(                          \
    (const __attribute__((address_space(1))) void*)(g),                       \
    (__attribute__((address_space(3))) void*)(l), 16, 0, 0)

__device__ __forceinline__ short f2bf(float f) {
    __hip_bfloat16 h = __float2bfloat16(f);
    return *reinterpret_cast<short*>(&h);
}

// ---------------------------------------------------------------------------
// Kernel 1: gating. One wave per token: 8 logits, softmax, top-2, bucket.
// Also emits bf16 cast of x (xb). List entries store slot = 2*t + k.
// ---------------------------------------------------------------------------
__global__ __launch_bounds__(256) void moe_gating(
    const float* __restrict__ x, const float* __restrict__ gw,
    const float* __restrict__ gb, int* __restrict__ counts,
    int* __restrict__ slot_list, float* __restrict__ w_list,
    short* __restrict__ xb)
{
    __shared__ float xs[4][DM];
    const int wv = threadIdx.x >> 6, ln = threadIdx.x & 63;
    const int t = (blockIdx.x << 2) + wv;
    const float* xp = x + (size_t)t * DM;
    for (int i = ln; i < DM; i += 64) xs[wv][i] = xp[i];
    __syncthreads();

    // bf16 cast of this token's row
    short* xbrow = xb + (size_t)t * DM;
    for (int i = ln; i < DM; i += 64) xbrow[i] = f2bf(xs[wv][i]);

    const int e = ln & 7, g = ln >> 3;
    const float* wp = gw + e * DM;
    float acc = 0.f;
#pragma unroll 8
    for (int j = 0; j < 64; ++j) {
        const int d = g + (j << 3);
        acc = fmaf(xs[wv][d], wp[d], acc);
    }
    acc += __shfl_xor(acc, 8);
    acc += __shfl_xor(acc, 16);
    acc += __shfl_xor(acc, 32);
    const float logit = acc + gb[e];

    float lg[8];
#pragma unroll
    for (int j = 0; j < 8; ++j) lg[j] = __shfl(logit, j);

    if (ln == 0) {
        float m = lg[0];
#pragma unroll
        for (int j = 1; j < 8; ++j) m = fmaxf(m, lg[j]);
        float s = 0.f, ex[8];
#pragma unroll
        for (int j = 0; j < 8; ++j) { ex[j] = expf(lg[j] - m); s += ex[j]; }
        int i0 = 0;
#pragma unroll
        for (int j = 1; j < 8; ++j) if (lg[j] > lg[i0]) i0 = j;
        int i1 = (i0 == 0) ? 1 : 0;
#pragma unroll
        for (int j = 0; j < 8; ++j) if (j != i0 && lg[j] > lg[i1]) i1 = j;
        const float inv = 0.5f / s;
        const int p0 = atomicAdd(&counts[i0], 1);
        slot_list[i0 * TT + p0] = (t << 1);     w_list[i0 * TT + p0] = ex[i0] * inv;
        const int p1 = atomicAdd(&counts[i1], 1);
        slot_list[i1 * TT + p1] = (t << 1) | 1; w_list[i1 * TT + p1] = ex[i1] * inv;
    }
}

// ---------------------------------------------------------------------------
// Kernel 2: W[e][k][n] fp32 -> Wt[e][n][k] bf16 (one-time per call).
// ---------------------------------------------------------------------------
__global__ __launch_bounds__(256) void moe_wt(
    const float* __restrict__ W, short* __restrict__ Wt)
{
    __shared__ float t[64][65];
    const int e = blockIdx.z, n0 = blockIdx.x << 6, k0 = blockIdx.y << 6;
    const float* src = W + ((size_t)e * DM + k0) * DH + n0;
#pragma unroll
    for (int i = 0; i < 16; ++i) {
        const int idx = i * 256 + threadIdx.x;
        const int kk = idx >> 6, nn = idx & 63;
        t[kk][nn] = src[(size_t)kk * DH + nn];
    }
    __syncthreads();
    short* dst = Wt + ((size_t)e * DH + n0) * DM + k0;
#pragma unroll
    for (int i = 0; i < 16; ++i) {
        const int idx = i * 256 + threadIdx.x;
        const int nn = idx >> 6, kk = idx & 63;
        dst[(size_t)nn * DM + kk] = f2bf(t[kk][nn]);
    }
}

// ---------------------------------------------------------------------------
// Kernel 3: grouped bf16 MFMA GEMM. Tile 128x128, BK=64, 4 waves, 64x64/wave,
// mfma_f32_16x16x32_bf16 4x4 frags. global_load_lds(16B) staging with
// XOR chunk swizzle (inverse swizzle applied on per-lane GLOBAL source,
// LDS dest linear; same XOR on ds_read side).
// GPATH=1: write G[slot][n] (no atomics). GPATH=0: unsafeAtomicAdd into out.
// ---------------------------------------------------------------------------
template <int GPATH>
__global__ __launch_bounds__(256) void moe_gemm_mfma(
    const short* __restrict__ xb, const short* __restrict__ Wt,
    const float* __restrict__ Bb, const int* __restrict__ counts,
    const int* __restrict__ slot_list, const float* __restrict__ w_list,
    float* __restrict__ G, float* __restrict__ out)
{
    const int e = blockIdx.z;
    const int cnt = counts[e];
    const int row0 = blockIdx.y << 7;
    if (row0 >= cnt) return;
    const int rem = cnt - row0;
    const int h0 = blockIdx.x << 7;

    __shared__ short As[128 * 64];   // [row][k] chunk-swizzled
    __shared__ short Bs[128 * 64];   // [n-row][k] chunk-swizzled
    __shared__ int   slot_s[128];
    __shared__ float wgt_s[128];

    const int tid = threadIdx.x;
    if (tid < 128) {
        const int ok = tid < rem;
        slot_s[tid] = ok ? slot_list[e * TT + row0 + tid] : 0;
        wgt_s[tid]  = ok ? w_list[e * TT + row0 + tid] : 0.f;
    }
    __syncthreads();

    const int wid = tid >> 6, lane = tid & 63;
    const int wm = wid >> 1, wn = wid & 1;

    // Staging: 1024 16B-chunks per tile, 4 per thread. chunk c -> row c>>3,
    // chunk-in-row cc = c&7; source k-chunk = cc ^ (row&7) (inverse swizzle).
    int a_srcoff[4], b_srcoff[4];
#pragma unroll
    for (int i = 0; i < 4; ++i) {
        const int c = i * 256 + wid * 64 + lane;
        const int r = c >> 3, cc = c & 7;
        const int tok = slot_s[r] >> 1;
        a_srcoff[i] = tok * DM + (((cc ^ (r & 7)) << 3));
        b_srcoff[i] = (h0 + r) * DM + (((cc ^ (r & 7)) << 3));
    }
    const short* We = Wt + (size_t)e * DH * DM;

    f32x4 acc[4][4];
#pragma unroll
    for (int mi = 0; mi < 4; ++mi)
#pragma unroll
        for (int ni = 0; ni < 4; ++ni)
            acc[mi][ni] = (f32x4){0.f, 0.f, 0.f, 0.f};

    for (int k0 = 0; k0 < DM; k0 += 64) {
        __syncthreads();   // previous compute done before overwrite
#pragma unroll
        for (int i = 0; i < 4; ++i) {
            const int dbase = (i * 256 + wid * 64) << 3;   // elements
            GL16(xb + a_srcoff[i] + k0, As + dbase);
            GL16(We + b_srcoff[i] + k0, Bs + dbase);
        }
        __syncthreads();   // drains vmcnt

#pragma unroll
        for (int kk = 0; kk < 2; ++kk) {
            short8 a[4], b[4];
#pragma unroll
            for (int mi = 0; mi < 4; ++mi) {
                const int r = wm * 64 + mi * 16 + (lane & 15);
                const int c = kk * 4 + (lane >> 4);
                a[mi] = *(const short8*)&As[r * 64 + ((c ^ (r & 7)) << 3)];
            }
#pragma unroll
            for (int ni = 0; ni < 4; ++ni) {
                const int r = wn * 64 + ni * 16 + (lane & 15);
                const int c = kk * 4 + (lane >> 4);
                b[ni] = *(const short8*)&Bs[r * 64 + ((c ^ (r & 7)) << 3)];
            }
#pragma unroll
            for (int mi = 0; mi < 4; ++mi)
#pragma unroll
                for (int ni = 0; ni < 4; ++ni)
                    acc[mi][ni] = __builtin_amdgcn_mfma_f32_16x16x32_bf16(
                        a[mi], b[ni], acc[mi][ni], 0, 0, 0);
        }
    }

    // Epilogue: D row = (lane>>4)*4 + reg, col = lane&15  [m89 layout]
    const float* be = Bb + e * DH;
#pragma unroll
    for (int mi = 0; mi < 4; ++mi) {
#pragma unroll
        for (int r = 0; r < 4; ++r) {
            const int rl = wm * 64 + mi * 16 + (lane >> 4) * 4 + r;
            if (rl < rem) {
                const float w = wgt_s[rl];
                const int slot = slot_s[rl];
#pragma unroll
                for (int ni = 0; ni < 4; ++ni) {
                    const int col = h0 + wn * 64 + ni * 16 + (lane & 15);
                    const float v = w * (acc[mi][ni][r] + be[col]);
                    if (GPATH)
                        G[(size_t)slot * DH + col] = v;
                    else
                        unsafeAtomicAdd(&out[(size_t)(slot >> 1) * DH + col], v);
                }
            }
        }
    }
}

// ---------------------------------------------------------------------------
// Kernel 4: combine — out[t] = G[2t] + G[2t+1], float4.
// ---------------------------------------------------------------------------
__global__ __launch_bounds__(256) void moe_combine(
    const float* __restrict__ G, float* __restrict__ out)
{
    const int n4 = TT * DH / 4;
    for (int i = blockIdx.x * 256 + threadIdx.x; i < n4; i += gridDim.x * 256) {
        const int f = i << 2;
        const int t = f >> 11;          // DH = 2048
        const int h = f & 2047;
        const float4 a = *(const float4*)&G[((size_t)(t << 1)) * DH + h];
        const float4 b = *(const float4*)&G[((size_t)(t << 1) + 1) * DH + h];
        float4 o;
        o.x = a.x + b.x; o.y = a.y + b.y; o.z = a.z + b.z; o.w = a.w + b.w;
        *(float4*)&out[f] = o;
    }
}

// ---------------------------------------------------------------------------
extern "C" void kernel_launch(void* const* d_in, const int* in_sizes, int n_in,
                              void* d_out, int out_size, void* d_ws, size_t ws_size,
                              hipStream_t stream) {
    const float* seq = (const float*)d_in[0];
    const float* ew  = (const float*)d_in[1];
    const float* eb  = (const float*)d_in[2];
    const float* gw  = (const float*)d_in[3];
    const float* gb  = (const float*)d_in[4];
    float* out = (float*)d_out;

    char* ws = (char*)d_ws;
    size_t off = 0;
    int* counts = (int*)(ws + off);           off += 1024;
    int* slot_list = (int*)(ws + off);        off += (size_t)NE * TT * 4;
    float* w_list = (float*)(ws + off);       off += (size_t)NE * TT * 4;
    short* xb = (short*)(ws + off);           off += (size_t)TT * DM * 2;
    short* Wt = (short*)(ws + off);           off += (size_t)NE * DH * DM * 2;
    float* G = (float*)(ws + off);
    const size_t need_g = off + (size_t)TT * 2 * DH * 4;
    const int gpath = (ws_size >= need_g);

    hipMemsetAsync(counts, 0, NE * sizeof(int), stream);
    if (!gpath)
        hipMemsetAsync(out, 0, (size_t)TT * DH * sizeof(float), stream);

    moe_gating<<<TT / 4, 256, 0, stream>>>(seq, gw, gb, counts, slot_list, w_list, xb);
    moe_wt<<<dim3(DH / 64, DM / 64, NE), 256, 0, stream>>>(ew, Wt);

    dim3 grid(DH / 128, TT / 128, NE);
    if (gpath) {
        moe_gemm_mfma<1><<<grid, 256, 0, stream>>>(xb, Wt, eb, counts, slot_list,
                                                   w_list, G, out);
        moe_combine<<<2048, 256, 0, stream>>>(G, out);
    } else {
        moe_gemm_mfma<0><<<grid, 256, 0, stream>>>(xb, Wt, eb, counts, slot_list,
                                                   w_list, G, out);
    }
}

// Round 10
// 262.418 us; speedup vs baseline: 3.1955x; 1.5751x over previous
//
#include <hip/hip_runtime.h>
#include <hip/hip_bf16.h>

#define TT 8192      // tokens = N*P
#define DM 512       // d_model
#define DH 2048      // d_inner
#define NE 8         // experts
#define GB_TOK 16    // tokens per gating block
// TOP_K = 2 folded into gate weights as *0.5f

typedef short short8 __attribute__((ext_vector_type(8)));
typedef short short4b __attribute__((ext_vector_type(4)));
typedef float f32x4  __attribute__((ext_vector_type(4)));

#define GL16(g, l) __builtin_amdgcn_global_load_lds(                          \
    (const __attribute__((address_space(1))) void*)(g),                       \
    (__attribute__((address_space(3))) void*)(l), 16, 0, 0)

__device__ __forceinline__ short f2bf(float f) {
    __hip_bfloat16 h = __float2bfloat16(f);
    return *reinterpret_cast<short*>(&h);
}

// ---------------------------------------------------------------------------
// Kernel 1: gating. 512 blocks x 16 tokens. One wave per token-slot, 4 tokens
// per wave sequentially. Entries staged in LDS; ONE global atomic per expert
// per block, counters padded to separate 64B lines (counts[e*16]) to kill the
// same-line atomic serialization that cost 206us in round 6.
// ---------------------------------------------------------------------------
__global__ __launch_bounds__(256) void moe_gating(
    const float* __restrict__ x, const float* __restrict__ gw,
    const float* __restrict__ gb, int* __restrict__ counts,
    int* __restrict__ slot_list, float* __restrict__ w_list,
    short* __restrict__ xb)
{
    __shared__ float xs[4][DM];
    __shared__ int   ent_e[2 * GB_TOK];
    __shared__ int   ent_t[2 * GB_TOK];
    __shared__ float ent_w[2 * GB_TOK];
    __shared__ int   rank_s[2 * GB_TOK];
    __shared__ int   base_s[NE];

    const int wv = threadIdx.x >> 6, ln = threadIdx.x & 63;
    const int e = ln & 7, g = ln >> 3;
    const float* wp = gw + e * DM;

#pragma unroll
    for (int it = 0; it < GB_TOK / 4; ++it) {
        const int t = blockIdx.x * GB_TOK + wv * (GB_TOK / 4) + it;
        const float* xp = x + (size_t)t * DM;
        short* xbrow = xb + (size_t)t * DM;
        for (int i = ln; i < DM; i += 64) {
            const float v = xp[i];
            xs[wv][i] = v;
            xbrow[i] = f2bf(v);
        }
        __syncthreads();   // uniform across waves (4 iters each)

        float acc = 0.f;
#pragma unroll 8
        for (int j = 0; j < 64; ++j) {
            const int d = g + (j << 3);
            acc = fmaf(xs[wv][d], wp[d], acc);
        }
        acc += __shfl_xor(acc, 8);
        acc += __shfl_xor(acc, 16);
        acc += __shfl_xor(acc, 32);
        const float logit = acc + gb[e];

        float lg[8];
#pragma unroll
        for (int j = 0; j < 8; ++j) lg[j] = __shfl(logit, j);

        if (ln == 0) {
            float m = lg[0];
#pragma unroll
            for (int j = 1; j < 8; ++j) m = fmaxf(m, lg[j]);
            float s = 0.f, ex[8];
#pragma unroll
            for (int j = 0; j < 8; ++j) { ex[j] = expf(lg[j] - m); s += ex[j]; }
            int i0 = 0;
#pragma unroll
            for (int j = 1; j < 8; ++j) if (lg[j] > lg[i0]) i0 = j;
            int i1 = (i0 == 0) ? 1 : 0;
#pragma unroll
            for (int j = 0; j < 8; ++j) if (j != i0 && lg[j] > lg[i1]) i1 = j;
            const float inv = 0.5f / s;
            const int sl = (wv * (GB_TOK / 4) + it) << 1;
            ent_e[sl]     = i0; ent_t[sl]     = (t << 1);     ent_w[sl]     = ex[i0] * inv;
            ent_e[sl + 1] = i1; ent_t[sl + 1] = (t << 1) | 1; ent_w[sl + 1] = ex[i1] * inv;
        }
        __syncthreads();
    }

    // per-expert count + rank (8 threads scan 32 entries), 1 atomic/expert
    if (threadIdx.x < NE) {
        const int me = threadIdx.x;
        int n = 0;
        for (int i = 0; i < 2 * GB_TOK; ++i)
            if (ent_e[i] == me) rank_s[i] = n++;
        base_s[me] = n ? atomicAdd(&counts[me << 4], n) : 0;
    }
    __syncthreads();
    if (threadIdx.x < 2 * GB_TOK) {
        const int i = threadIdx.x;
        const int ee = ent_e[i];
        const int pos = ee * TT + base_s[ee] + rank_s[i];
        slot_list[pos] = ent_t[i];
        w_list[pos]    = ent_w[i];
    }
}

// ---------------------------------------------------------------------------
// Kernel 2: W[e][k][n] fp32 -> Wt[e][n][k] bf16. short4 (8B) stores.
// ---------------------------------------------------------------------------
__global__ __launch_bounds__(256) void moe_wt(
    const float* __restrict__ W, short* __restrict__ Wt)
{
    __shared__ float t[64][65];
    const int e = blockIdx.z, n0 = blockIdx.x << 6, k0 = blockIdx.y << 6;
    const float* src = W + ((size_t)e * DM + k0) * DH + n0;
#pragma unroll
    for (int i = 0; i < 16; ++i) {
        const int idx = i * 256 + threadIdx.x;
        const int kk = idx >> 6, nn = idx & 63;
        t[kk][nn] = src[(size_t)kk * DH + nn];
    }
    __syncthreads();
    short* dst = Wt + ((size_t)e * DH + n0) * DM + k0;
#pragma unroll
    for (int i = 0; i < 4; ++i) {
        const int nn = i * 16 + (threadIdx.x >> 4);
        const int kk = (threadIdx.x & 15) << 2;
        short4b v;
#pragma unroll
        for (int c = 0; c < 4; ++c) v[c] = f2bf(t[kk + c][nn]);
        *(short4b*)&dst[(size_t)nn * DM + kk] = v;
    }
}

// ---------------------------------------------------------------------------
// Kernel 3: grouped bf16 MFMA GEMM. Tile 128x128, BK=64, 4 waves, 64x64/wave,
// mfma_f32_16x16x32_bf16 4x4 frags. global_load_lds(16B) staging with
// XOR chunk swizzle (inverse swizzle on per-lane GLOBAL source, LDS dest
// linear; same XOR on ds_read side).
// ---------------------------------------------------------------------------
template <int GPATH>
__global__ __launch_bounds__(256) void moe_gemm_mfma(
    const short* __restrict__ xb, const short* __restrict__ Wt,
    const float* __restrict__ Bb, const int* __restrict__ counts,
    const int* __restrict__ slot_list, const float* __restrict__ w_list,
    float* __restrict__ G, float* __restrict__ out)
{
    const int e = blockIdx.z;
    const int cnt = counts[e << 4];
    const int row0 = blockIdx.y << 7;
    if (row0 >= cnt) return;
    const int rem = cnt - row0;
    const int h0 = blockIdx.x << 7;

    __shared__ short As[128 * 64];
    __shared__ short Bs[128 * 64];
    __shared__ int   slot_s[128];
    __shared__ float wgt_s[128];

    const int tid = threadIdx.x;
    if (tid < 128) {
        const int ok = tid < rem;
        slot_s[tid] = ok ? slot_list[e * TT + row0 + tid] : 0;
        wgt_s[tid]  = ok ? w_list[e * TT + row0 + tid] : 0.f;
    }
    __syncthreads();

    const int wid = tid >> 6, lane = tid & 63;
    const int wm = wid >> 1, wn = wid & 1;

    int a_srcoff[4], b_srcoff[4];
#pragma unroll
    for (int i = 0; i < 4; ++i) {
        const int c = i * 256 + wid * 64 + lane;
        const int r = c >> 3, cc = c & 7;
        const int tok = slot_s[r] >> 1;
        a_srcoff[i] = tok * DM + (((cc ^ (r & 7)) << 3));
        b_srcoff[i] = (h0 + r) * DM + (((cc ^ (r & 7)) << 3));
    }
    const short* We = Wt + (size_t)e * DH * DM;

    f32x4 acc[4][4];
#pragma unroll
    for (int mi = 0; mi < 4; ++mi)
#pragma unroll
        for (int ni = 0; ni < 4; ++ni)
            acc[mi][ni] = (f32x4){0.f, 0.f, 0.f, 0.f};

    for (int k0 = 0; k0 < DM; k0 += 64) {
        __syncthreads();
#pragma unroll
        for (int i = 0; i < 4; ++i) {
            const int dbase = (i * 256 + wid * 64) << 3;
            GL16(xb + a_srcoff[i] + k0, As + dbase);
            GL16(We + b_srcoff[i] + k0, Bs + dbase);
        }
        __syncthreads();

#pragma unroll
        for (int kk = 0; kk < 2; ++kk) {
            short8 a[4], b[4];
#pragma unroll
            for (int mi = 0; mi < 4; ++mi) {
                const int r = wm * 64 + mi * 16 + (lane & 15);
                const int c = kk * 4 + (lane >> 4);
                a[mi] = *(const short8*)&As[r * 64 + ((c ^ (r & 7)) << 3)];
            }
#pragma unroll
            for (int ni = 0; ni < 4; ++ni) {
                const int r = wn * 64 + ni * 16 + (lane & 15);
                const int c = kk * 4 + (lane >> 4);
                b[ni] = *(const short8*)&Bs[r * 64 + ((c ^ (r & 7)) << 3)];
            }
#pragma unroll
            for (int mi = 0; mi < 4; ++mi)
#pragma unroll
                for (int ni = 0; ni < 4; ++ni)
                    acc[mi][ni] = __builtin_amdgcn_mfma_f32_16x16x32_bf16(
                        a[mi], b[ni], acc[mi][ni], 0, 0, 0);
        }
    }

    const float* be = Bb + e * DH;
#pragma unroll
    for (int mi = 0; mi < 4; ++mi) {
#pragma unroll
        for (int r = 0; r < 4; ++r) {
            const int rl = wm * 64 + mi * 16 + (lane >> 4) * 4 + r;
            if (rl < rem) {
                const float w = wgt_s[rl];
                const int slot = slot_s[rl];
#pragma unroll
                for (int ni = 0; ni < 4; ++ni) {
                    const int col = h0 + wn * 64 + ni * 16 + (lane & 15);
                    const float v = w * (acc[mi][ni][r] + be[col]);
                    if (GPATH)
                        G[(size_t)slot * DH + col] = v;
                    else
                        unsafeAtomicAdd(&out[(size_t)(slot >> 1) * DH + col], v);
                }
            }
        }
    }
}

// ---------------------------------------------------------------------------
// Kernel 4: combine — out[t] = G[2t] + G[2t+1], float4.
// ---------------------------------------------------------------------------
__global__ __launch_bounds__(256) void moe_combine(
    const float* __restrict__ G, float* __restrict__ out)
{
    const int n4 = TT * DH / 4;
    for (int i = blockIdx.x * 256 + threadIdx.x; i < n4; i += gridDim.x * 256) {
        const int f = i << 2;
        const int t = f >> 11;
        const int h = f & 2047;
        const float4 a = *(const float4*)&G[((size_t)(t << 1)) * DH + h];
        const float4 b = *(const float4*)&G[((size_t)(t << 1) + 1) * DH + h];
        float4 o;
        o.x = a.x + b.x; o.y = a.y + b.y; o.z = a.z + b.z; o.w = a.w + b.w;
        *(float4*)&out[f] = o;
    }
}

// ---------------------------------------------------------------------------
extern "C" void kernel_launch(void* const* d_in, const int* in_sizes, int n_in,
                              void* d_out, int out_size, void* d_ws, size_t ws_size,
                              hipStream_t stream) {
    const float* seq = (const float*)d_in[0];
    const float* ew  = (const float*)d_in[1];
    const float* eb  = (const float*)d_in[2];
    const float* gw  = (const float*)d_in[3];
    const float* gb  = (const float*)d_in[4];
    float* out = (float*)d_out;

    char* ws = (char*)d_ws;
    size_t off = 0;
    int* counts = (int*)(ws + off);           off += 1024;   // padded: counts[e*16]
    int* slot_list = (int*)(ws + off);        off += (size_t)NE * TT * 4;
    float* w_list = (float*)(ws + off);       off += (size_t)NE * TT * 4;
    short* xb = (short*)(ws + off);           off += (size_t)TT * DM * 2;
    short* Wt = (short*)(ws + off);           off += (size_t)NE * DH * DM * 2;
    float* G = (float*)(ws + off);
    const size_t need_g = off + (size_t)TT * 2 * DH * 4;
    const int gpath = (ws_size >= need_g);

    hipMemsetAsync(counts, 0, 1024, stream);
    if (!gpath)
        hipMemsetAsync(out, 0, (size_t)TT * DH * sizeof(float), stream);

    moe_gating<<<TT / GB_TOK, 256, 0, stream>>>(seq, gw, gb, counts, slot_list,
                                                w_list, xb);
    moe_wt<<<dim3(DH / 64, DM / 64, NE), 256, 0, stream>>>(ew, Wt);

    dim3 grid(DH / 128, TT / 128, NE);
    if (gpath) {
        moe_gemm_mfma<1><<<grid, 256, 0, stream>>>(xb, Wt, eb, counts, slot_list,
                                                   w_list, G, out);
        moe_combine<<<2048, 256, 0, stream>>>(G, out);
    } else {
        moe_gemm_mfma<0><<<grid, 256, 0, stream>>>(xb, Wt, eb, counts, slot_list,
                                                   w_list, G, out);
    }
}

// Round 14
// 235.284 us; speedup vs baseline: 3.5640x; 1.1153x over previous
//
#include <hip/hip_runtime.h>
#include <hip/hip_bf16.h>

#define TT 8192      // tokens = N*P
#define DM 512       // d_model
#define DH 2048      // d_inner
#define NE 8         // experts
#define GB_TOK 16    // tokens per gating block
// TOP_K = 2 folded into gate weights as *0.5f

typedef short short8 __attribute__((ext_vector_type(8)));
typedef short short4b __attribute__((ext_vector_type(4)));
typedef float f32x4  __attribute__((ext_vector_type(4)));

#define GL16(g, l) __builtin_amdgcn_global_load_lds(                          \
    (const __attribute__((address_space(1))) void*)(g),                       \
    (__attribute__((address_space(3))) void*)(l), 16, 0, 0)

__device__ __forceinline__ short f2bf(float f) {
    __hip_bfloat16 h = __float2bfloat16(f);
    return *reinterpret_cast<short*>(&h);
}
__device__ __forceinline__ float bf2f(short s) {
    union { unsigned u; float f; } v;
    v.u = ((unsigned)(unsigned short)s) << 16;
    return v.f;
}

// ---------------------------------------------------------------------------
// Kernel 1: gating. 512 blocks x 16 tokens; LDS bucketing, 1 atomic per
// expert per block on 64B-padded counters (round-6 fix, verified round 10).
// ---------------------------------------------------------------------------
__global__ __launch_bounds__(256) void moe_gating(
    const float* __restrict__ x, const float* __restrict__ gw,
    const float* __restrict__ gb, int* __restrict__ counts,
    int* __restrict__ slot_list, float* __restrict__ w_list,
    short* __restrict__ xb)
{
    __shared__ float xs[4][DM];
    __shared__ int   ent_e[2 * GB_TOK];
    __shared__ int   ent_t[2 * GB_TOK];
    __shared__ float ent_w[2 * GB_TOK];
    __shared__ int   rank_s[2 * GB_TOK];
    __shared__ int   base_s[NE];

    const int wv = threadIdx.x >> 6, ln = threadIdx.x & 63;
    const int e = ln & 7, g = ln >> 3;
    const float* wp = gw + e * DM;

#pragma unroll
    for (int it = 0; it < GB_TOK / 4; ++it) {
        const int t = blockIdx.x * GB_TOK + wv * (GB_TOK / 4) + it;
        const float* xp = x + (size_t)t * DM;
        short* xbrow = xb + (size_t)t * DM;
        for (int i = ln; i < DM; i += 64) {
            const float v = xp[i];
            xs[wv][i] = v;
            xbrow[i] = f2bf(v);
        }
        __syncthreads();   // uniform across waves (4 iters each)

        float acc = 0.f;
#pragma unroll 8
        for (int j = 0; j < 64; ++j) {
            const int d = g + (j << 3);
            acc = fmaf(xs[wv][d], wp[d], acc);
        }
        acc += __shfl_xor(acc, 8);
        acc += __shfl_xor(acc, 16);
        acc += __shfl_xor(acc, 32);
        const float logit = acc + gb[e];

        float lg[8];
#pragma unroll
        for (int j = 0; j < 8; ++j) lg[j] = __shfl(logit, j);

        if (ln == 0) {
            float m = lg[0];
#pragma unroll
            for (int j = 1; j < 8; ++j) m = fmaxf(m, lg[j]);
            float s = 0.f, ex[8];
#pragma unroll
            for (int j = 0; j < 8; ++j) { ex[j] = expf(lg[j] - m); s += ex[j]; }
            int i0 = 0;
#pragma unroll
            for (int j = 1; j < 8; ++j) if (lg[j] > lg[i0]) i0 = j;
            int i1 = (i0 == 0) ? 1 : 0;
#pragma unroll
            for (int j = 0; j < 8; ++j) if (j != i0 && lg[j] > lg[i1]) i1 = j;
            const float inv = 0.5f / s;
            const int sl = (wv * (GB_TOK / 4) + it) << 1;
            ent_e[sl]     = i0; ent_t[sl]     = (t << 1);     ent_w[sl]     = ex[i0] * inv;
            ent_e[sl + 1] = i1; ent_t[sl + 1] = (t << 1) | 1; ent_w[sl + 1] = ex[i1] * inv;
        }
        __syncthreads();
    }

    if (threadIdx.x < NE) {
        const int me = threadIdx.x;
        int n = 0;
        for (int i = 0; i < 2 * GB_TOK; ++i)
            if (ent_e[i] == me) rank_s[i] = n++;
        base_s[me] = n ? atomicAdd(&counts[me << 4], n) : 0;
    }
    __syncthreads();
    if (threadIdx.x < 2 * GB_TOK) {
        const int i = threadIdx.x;
        const int ee = ent_e[i];
        const int pos = ee * TT + base_s[ee] + rank_s[i];
        slot_list[pos] = ent_t[i];
        w_list[pos]    = ent_w[i];
    }
}

// ---------------------------------------------------------------------------
// Kernel 2: W[e][k][n] fp32 -> Wt[e][n][k] bf16. short4 (8B) stores.
// ---------------------------------------------------------------------------
__global__ __launch_bounds__(256) void moe_wt(
    const float* __restrict__ W, short* __restrict__ Wt)
{
    __shared__ float t[64][65];
    const int e = blockIdx.z, n0 = blockIdx.x << 6, k0 = blockIdx.y << 6;
    const float* src = W + ((size_t)e * DM + k0) * DH + n0;
#pragma unroll
    for (int i = 0; i < 16; ++i) {
        const int idx = i * 256 + threadIdx.x;
        const int kk = idx >> 6, nn = idx & 63;
        t[kk][nn] = src[(size_t)kk * DH + nn];
    }
    __syncthreads();
    short* dst = Wt + ((size_t)e * DH + n0) * DM + k0;
#pragma unroll
    for (int i = 0; i < 4; ++i) {
        const int nn = i * 16 + (threadIdx.x >> 4);
        const int kk = (threadIdx.x & 15) << 2;
        short4b v;
#pragma unroll
        for (int c = 0; c < 4; ++c) v[c] = f2bf(t[kk + c][nn]);
        *(short4b*)&dst[(size_t)nn * DM + kk] = v;
    }
}

// ---------------------------------------------------------------------------
// Kernel 3: grouped bf16 MFMA GEMM, 2-PHASE double-buffered (T3-minimum):
// issue next K-tile's global_load_lds into buf^1 BEFORE computing buf; the
// single __syncthreads per K-step drains vmcnt, so load latency hides under
// 32 MFMAs + ds_reads. XOR chunk swizzle unchanged (0 bank conflicts @ r10).
// Epilogue stores bf16 into G (halves G traffic).
// ---------------------------------------------------------------------------
template <int GPATH>
__global__ __launch_bounds__(256) void moe_gemm_mfma(
    const short* __restrict__ xb, const short* __restrict__ Wt,
    const float* __restrict__ Bb, const int* __restrict__ counts,
    const int* __restrict__ slot_list, const float* __restrict__ w_list,
    short* __restrict__ G, float* __restrict__ out)
{
    const int e = blockIdx.z;
    const int cnt = counts[e << 4];
    const int row0 = blockIdx.y << 7;
    if (row0 >= cnt) return;
    const int rem = cnt - row0;
    const int h0 = blockIdx.x << 7;

    __shared__ short As[2][128 * 64];
    __shared__ short Bs[2][128 * 64];
    __shared__ int   slot_s[128];
    __shared__ float wgt_s[128];

    const int tid = threadIdx.x;
    if (tid < 128) {
        const int ok = tid < rem;
        slot_s[tid] = ok ? slot_list[e * TT + row0 + tid] : 0;
        wgt_s[tid]  = ok ? w_list[e * TT + row0 + tid] : 0.f;
    }
    __syncthreads();

    const int wid = tid >> 6, lane = tid & 63;
    const int wm = wid >> 1, wn = wid & 1;

    int a_srcoff[4], b_srcoff[4], dbase[4];
#pragma unroll
    for (int i = 0; i < 4; ++i) {
        const int c = i * 256 + wid * 64 + lane;
        const int r = c >> 3, cc = c & 7;
        const int tok = slot_s[r] >> 1;
        a_srcoff[i] = tok * DM + (((cc ^ (r & 7)) << 3));
        b_srcoff[i] = (h0 + r) * DM + (((cc ^ (r & 7)) << 3));
        dbase[i] = (i * 256 + wid * 64) << 3;
    }
    const short* We = Wt + (size_t)e * DH * DM;

    f32x4 acc[4][4];
#pragma unroll
    for (int mi = 0; mi < 4; ++mi)
#pragma unroll
        for (int ni = 0; ni < 4; ++ni)
            acc[mi][ni] = (f32x4){0.f, 0.f, 0.f, 0.f};

#define STAGE(buf, k0)                                                        \
    _Pragma("unroll")                                                         \
    for (int i = 0; i < 4; ++i) {                                             \
        GL16(xb + a_srcoff[i] + (k0), &As[buf][dbase[i]]);                    \
        GL16(We + b_srcoff[i] + (k0), &Bs[buf][dbase[i]]);                    \
    }

#define COMPUTE(buf)                                                          \
    _Pragma("unroll")                                                         \
    for (int kk = 0; kk < 2; ++kk) {                                          \
        short8 a[4], b[4];                                                    \
        _Pragma("unroll")                                                     \
        for (int mi = 0; mi < 4; ++mi) {                                      \
            const int r = wm * 64 + mi * 16 + (lane & 15);                    \
            const int c = kk * 4 + (lane >> 4);                               \
            a[mi] = *(const short8*)&As[buf][r * 64 + ((c ^ (r & 7)) << 3)];  \
        }                                                                     \
        _Pragma("unroll")                                                     \
        for (int ni = 0; ni < 4; ++ni) {                                      \
            const int r = wn * 64 + ni * 16 + (lane & 15);                    \
            const int c = kk * 4 + (lane >> 4);                               \
            b[ni] = *(const short8*)&Bs[buf][r * 64 + ((c ^ (r & 7)) << 3)];  \
        }                                                                     \
        _Pragma("unroll")                                                     \
        for (int mi = 0; mi < 4; ++mi)                                        \
            _Pragma("unroll")                                                 \
            for (int ni = 0; ni < 4; ++ni)                                    \
                acc[mi][ni] = __builtin_amdgcn_mfma_f32_16x16x32_bf16(        \
                    a[mi], b[ni], acc[mi][ni], 0, 0, 0);                      \
    }

    // prologue: stage K-tile 0, wait for it
    STAGE(0, 0)
    __syncthreads();           // vmcnt(0) drain + barrier

    // 2-phase main loop: 8 K-steps total
#pragma unroll
    for (int kt = 0; kt < (DM / 64) - 1; ++kt) {
        const int cur = kt & 1;
        STAGE(cur ^ 1, (kt + 1) * 64)   // next tile in flight...
        COMPUTE(cur)                    // ...under this tile's compute
        __syncthreads();                // drain next tile's loads + sync
    }
    COMPUTE(((DM / 64) - 1) & 1)        // last tile, no prefetch

#undef STAGE
#undef COMPUTE

    // Epilogue: D row = (lane>>4)*4 + reg, col = lane&15  [m89 layout]
    const float* be = Bb + e * DH;
#pragma unroll
    for (int mi = 0; mi < 4; ++mi) {
#pragma unroll
        for (int r = 0; r < 4; ++r) {
            const int rl = wm * 64 + mi * 16 + (lane >> 4) * 4 + r;
            if (rl < rem) {
                const float w = wgt_s[rl];
                const int slot = slot_s[rl];
#pragma unroll
                for (int ni = 0; ni < 4; ++ni) {
                    const int col = h0 + wn * 64 + ni * 16 + (lane & 15);
                    const float v = w * (acc[mi][ni][r] + be[col]);
                    if (GPATH)
                        G[(size_t)slot * DH + col] = f2bf(v);
                    else
                        unsafeAtomicAdd(&out[(size_t)(slot >> 1) * DH + col], v);
                }
            }
        }
    }
}

// ---------------------------------------------------------------------------
// Kernel 4: combine — out[t] = G[2t] + G[2t+1] (bf16 in, fp32 out), 8/thread.
// ---------------------------------------------------------------------------
__global__ __launch_bounds__(256) void moe_combine(
    const short* __restrict__ G, float* __restrict__ out)
{
    const int n8 = TT * DH / 8;
    for (int i = blockIdx.x * 256 + threadIdx.x; i < n8; i += gridDim.x * 256) {
        const int f = i << 3;
        const int t = f >> 11;          // DH = 2048
        const int h = f & 2047;
        const short8 a = *(const short8*)&G[((size_t)(t << 1)) * DH + h];
        const short8 b = *(const short8*)&G[((size_t)(t << 1) + 1) * DH + h];
        float4 o0, o1;
        o0.x = bf2f(a[0]) + bf2f(b[0]);
        o0.y = bf2f(a[1]) + bf2f(b[1]);
        o0.z = bf2f(a[2]) + bf2f(b[2]);
        o0.w = bf2f(a[3]) + bf2f(b[3]);
        o1.x = bf2f(a[4]) + bf2f(b[4]);
        o1.y = bf2f(a[5]) + bf2f(b[5]);
        o1.z = bf2f(a[6]) + bf2f(b[6]);
        o1.w = bf2f(a[7]) + bf2f(b[7]);
        *(float4*)&out[f]     = o0;
        *(float4*)&out[f + 4] = o1;
    }
}

// ---------------------------------------------------------------------------
extern "C" void kernel_launch(void* const* d_in, const int* in_sizes, int n_in,
                              void* d_out, int out_size, void* d_ws, size_t ws_size,
                              hipStream_t stream) {
    const float* seq = (const float*)d_in[0];
    const float* ew  = (const float*)d_in[1];
    const float* eb  = (const float*)d_in[2];
    const float* gw  = (const float*)d_in[3];
    const float* gb  = (const float*)d_in[4];
    float* out = (float*)d_out;

    char* ws = (char*)d_ws;
    size_t off = 0;
    int* counts = (int*)(ws + off);           off += 1024;   // padded: counts[e*16]
    int* slot_list = (int*)(ws + off);        off += (size_t)NE * TT * 4;
    float* w_list = (float*)(ws + off);       off += (size_t)NE * TT * 4;
    short* xb = (short*)(ws + off);           off += (size_t)TT * DM * 2;
    short* Wt = (short*)(ws + off);           off += (size_t)NE * DH * DM * 2;
    short* G = (short*)(ws + off);
    const size_t need_g = off + (size_t)TT * 2 * DH * 2;     // bf16 G
    const int gpath = (ws_size >= need_g);

    hipMemsetAsync(counts, 0, 1024, stream);
    if (!gpath)
        hipMemsetAsync(out, 0, (size_t)TT * DH * sizeof(float), stream);

    moe_gating<<<TT / GB_TOK, 256, 0, stream>>>(seq, gw, gb, counts, slot_list,
                                                w_list, xb);
    moe_wt<<<dim3(DH / 64, DM / 64, NE), 256, 0, stream>>>(ew, Wt);

    dim3 grid(DH / 128, TT / 128, NE);
    if (gpath) {
        moe_gemm_mfma<1><<<grid, 256, 0, stream>>>(xb, Wt, eb, counts, slot_list,
                                                   w_list, G, out);
        moe_combine<<<1024, 256, 0, stream>>>(G, out);
    } else {
        moe_gemm_mfma<0><<<grid, 256, 0, stream>>>(xb, Wt, eb, counts, slot_list,
                                                   w_list, G, out);
    }
}